// Round 1
// baseline (63819.531 us; speedup 1.0000x reference)
//
#include <hip/hip_runtime.h>
#include <stdint.h>

#define SEQ   512
#define BATCH 64
#define INP   64
#define HID   1024
#define NBLK  512     // 512 blocks, 2 hidden units each
#define NTHR  128     // 2 units x 64 batch

// ---- grid-wide barrier: flag-array, poison-safe, device-scope ----
__device__ __forceinline__ void gbar(uint32_t* flags, uint32_t val, int tid) {
    __syncthreads();   // drains all block stores to L2 (vmcnt0) + exec sync
    if (tid == 0) {
        __threadfence();   // wbl2: make this XCD's dirty lines visible at coherence point
        __hip_atomic_store(&flags[blockIdx.x], val, __ATOMIC_RELAXED, __HIP_MEMORY_SCOPE_AGENT);
    }
    if (tid < 64) {
        for (;;) {
            bool ok = true;
            #pragma unroll
            for (int i = 0; i < NBLK / 64; ++i) {
                uint32_t v = __hip_atomic_load(&flags[tid + i * 64], __ATOMIC_RELAXED,
                                               __HIP_MEMORY_SCOPE_AGENT);
                // pass iff val <= v < val + 2^28  (0xAAAAAAAA poison and stale-phase values fail)
                ok &= ((uint32_t)(v - val) < 0x10000000u);
            }
            if (__all(ok)) break;
        }
    }
    if (tid == 0) __threadfence();  // acquire: invalidate L1/L2 so fresh h is read
    __syncthreads();
}

__device__ __forceinline__ float sigf(float x) { return 1.0f / (1.0f + __expf(-x)); }

// ================= Phase A: layer-0 scan =================
// block bk owns hidden units j = 2*bk + {0,1}; thread (u,b) owns (unit, batch).
// h stored transposed [k][b] in hbuf (double buffer). h1 output parked in d_out[t][b][j].
__global__ void __launch_bounds__(NTHR) lstm_phaseA(
    const float* __restrict__ x,   const float* __restrict__ Wih,
    const float* __restrict__ Whh, const float* __restrict__ bih,
    const float* __restrict__ bhh, float* __restrict__ out,
    float* __restrict__ hbuf, uint32_t* __restrict__ flags)
{
    __shared__ float Wh[2][HID][4];  // [u][k][gate]  32 KB
    __shared__ float Wi[2][INP][4];  //               2 KB
    const int tid = threadIdx.x;
    const int bk  = blockIdx.x;
    const int u   = tid >> 6;
    const int b   = tid & 63;
    const int j   = bk * 2 + u;

    // stage weight slices (coalesced over k)
    for (int idx = tid; idx < 2 * 4 * HID; idx += NTHR) {
        int uu = idx >> 12, rem = idx & 4095, g = rem >> 10, k = rem & 1023;
        Wh[uu][k][g] = Whh[((size_t)(g * HID + bk * 2 + uu)) * HID + k];
    }
    for (int idx = tid; idx < 2 * 4 * INP; idx += NTHR) {
        int uu = idx >> 8, rem = idx & 255, g = rem >> 6, k = rem & 63;
        Wi[uu][k][g] = Wih[(size_t)(g * HID + bk * 2 + uu) * INP + k];
    }
    float bias[4];
    #pragma unroll
    for (int g = 0; g < 4; ++g) bias[g] = bih[g * HID + j] + bhh[g * HID + j];

    hbuf[j * 64 + b] = 0.0f;   // h(-1) = 0 in buffer 0 (ws is poisoned)
    float c = 0.0f;
    gbar(flags, 1u, tid);

    for (int t = 0; t < SEQ; ++t) {
        const float* hr = hbuf + (t & 1) * (HID * 64);
        float*       hw = hbuf + ((t & 1) ^ 1) * (HID * 64);
        float a0 = bias[0], a1 = bias[1], a2 = bias[2], a3 = bias[3];

        // x-part (K=64): per-lane contiguous float4
        const float4* xr = (const float4*)(x + ((size_t)t * BATCH + b) * INP);
        #pragma unroll
        for (int k4 = 0; k4 < INP / 4; ++k4) {
            float4 xv = xr[k4];
            float xa[4] = {xv.x, xv.y, xv.z, xv.w};
            #pragma unroll
            for (int m = 0; m < 4; ++m) {
                float4 w = *(const float4*)&Wi[u][k4 * 4 + m][0];  // ds_read_b128 broadcast
                a0 += w.x * xa[m]; a1 += w.y * xa[m]; a2 += w.z * xa[m]; a3 += w.w * xa[m];
            }
        }
        // h-part (K=1024): coalesced dword h load + b128 broadcast weights
        #pragma unroll 16
        for (int k = 0; k < HID; ++k) {
            float  hv = hr[k * 64 + b];
            float4 w  = *(const float4*)&Wh[u][k][0];
            a0 += w.x * hv; a1 += w.y * hv; a2 += w.z * hv; a3 += w.w * hv;
        }
        float ig = sigf(a0), fg = sigf(a1), gg = tanhf(a2), og = sigf(a3);
        c = fg * c + ig * gg;
        float h = og * tanhf(c);
        hw[j * 64 + b] = h;
        out[((size_t)t * BATCH + b) * HID + j] = h;   // park h1 in d_out
        if (t < SEQ - 1) gbar(flags, (uint32_t)(t + 2), tid);  // last step: kernel-end release
    }
}

// ================= Phase B: layer-1 scan + y_pred =================
// x-input is h1_t read from d_out[t]; layer-1 h overwrites d_out[t] DEFERRED one step
// (written at step t+1 after the barrier, so all reads of h1_t are complete).
__global__ void __launch_bounds__(NTHR) lstm_phaseB(
    const float* __restrict__ Wih, const float* __restrict__ Whh,
    const float* __restrict__ bih, const float* __restrict__ bhh,
    const float* __restrict__ Wlin, const float* __restrict__ blin,
    float* __restrict__ out, float* __restrict__ hbuf, uint32_t* __restrict__ flags)
{
    __shared__ float W[2][2][HID][4];   // [ih/hh][u][k][gate] = 64 KB exactly
    const int tid = threadIdx.x, bk = blockIdx.x;
    const int u = tid >> 6, b = tid & 63;
    const int j = bk * 2 + u;

    for (int idx = tid; idx < 2 * 4 * HID; idx += NTHR) {
        int uu = idx >> 12, rem = idx & 4095, g = rem >> 10, k = rem & 1023;
        size_t ro = ((size_t)(g * HID + bk * 2 + uu)) * HID + k;
        W[0][uu][k][g] = Wih[ro];
        W[1][uu][k][g] = Whh[ro];
    }
    float bias[4];
    #pragma unroll
    for (int g = 0; g < 4; ++g) bias[g] = bih[g * HID + j] + bhh[g * HID + j];

    hbuf[j * 64 + b] = 0.0f;
    float c = 0.0f, hout = 0.0f;
    gbar(flags, 1u, tid);

    for (int t = 0; t < SEQ; ++t) {
        if (t > 0) out[((size_t)(t - 1) * BATCH + b) * HID + j] = hout;  // deferred h2 write
        const float* hr = hbuf + (t & 1) * (HID * 64);
        float*       hw = hbuf + ((t & 1) ^ 1) * (HID * 64);
        float a0 = bias[0], a1 = bias[1], a2 = bias[2], a3 = bias[3];

        // x-part (K=1024): h1_t from d_out, per-lane contiguous float4
        const float4* xr = (const float4*)(out + ((size_t)t * BATCH + b) * HID);
        #pragma unroll 8
        for (int k4 = 0; k4 < HID / 4; ++k4) {
            float4 xv = xr[k4];
            float xa[4] = {xv.x, xv.y, xv.z, xv.w};
            #pragma unroll
            for (int m = 0; m < 4; ++m) {
                float4 w = *(const float4*)&W[0][u][k4 * 4 + m][0];
                a0 += w.x * xa[m]; a1 += w.y * xa[m]; a2 += w.z * xa[m]; a3 += w.w * xa[m];
            }
        }
        // recurrent part (K=1024)
        #pragma unroll 16
        for (int k = 0; k < HID; ++k) {
            float  hv = hr[k * 64 + b];
            float4 w  = *(const float4*)&W[1][u][k][0];
            a0 += w.x * hv; a1 += w.y * hv; a2 += w.z * hv; a3 += w.w * hv;
        }
        float ig = sigf(a0), fg = sigf(a1), gg = tanhf(a2), og = sigf(a3);
        c = fg * c + ig * gg;
        float h = og * tanhf(c);
        hw[j * 64 + b] = h;
        hout = h;
        gbar(flags, (uint32_t)(t + 2), tid);
    }
    out[((size_t)(SEQ - 1) * BATCH + b) * HID + j] = hout;

    // y_pred = h2[T-1] @ W_lin^T + b_lin   (h2[T-1] is in hbuf buffer 0: ((511&1)^1)==0)
    if (bk == 0 && tid < 64) {
        float acc = blin[0];
        #pragma unroll 8
        for (int k = 0; k < HID; ++k) acc += hbuf[k * 64 + tid] * Wlin[k];
        out[(size_t)SEQ * BATCH * HID + tid] = acc;
    }
}

extern "C" void kernel_launch(void* const* d_in, const int* in_sizes, int n_in,
                              void* d_out, int out_size, void* d_ws, size_t ws_size,
                              hipStream_t stream) {
    const float* x     = (const float*)d_in[0];
    const float* Wih0  = (const float*)d_in[1];
    const float* Whh0  = (const float*)d_in[2];
    const float* bih0  = (const float*)d_in[3];
    const float* bhh0  = (const float*)d_in[4];
    const float* Wih1  = (const float*)d_in[5];
    const float* Whh1  = (const float*)d_in[6];
    const float* bih1  = (const float*)d_in[7];
    const float* bhh1  = (const float*)d_in[8];
    const float* Wlin  = (const float*)d_in[9];
    const float* blin  = (const float*)d_in[10];
    float* out = (float*)d_out;

    float* ws = (float*)d_ws;
    float* hA = ws;                       // 2 * 1024 * 64 floats
    float* hB = ws + 2 * HID * BATCH;     // 2 * 1024 * 64 floats
    uint32_t* flagsA = (uint32_t*)(ws + 4 * HID * BATCH);
    uint32_t* flagsB = flagsA + NBLK;

    lstm_phaseA<<<dim3(NBLK), dim3(NTHR), 0, stream>>>(
        x, Wih0, Whh0, bih0, bhh0, out, hA, flagsA);
    lstm_phaseB<<<dim3(NBLK), dim3(NTHR), 0, stream>>>(
        Wih1, Whh1, bih1, bhh1, Wlin, blin, out, hB, flagsB);
}